// Round 12
// baseline (268.737 us; speedup 1.0000x reference)
//
#include <hip/hip_runtime.h>
#include <hip/hip_bf16.h>

typedef __attribute__((ext_vector_type(8))) short short8;
typedef __attribute__((ext_vector_type(4))) float f32x4;
typedef __attribute__((ext_vector_type(16))) float f32x16;

#define B_   4
#define S_   2048
#define D_   1024
#define H_   16
#define HD_  64
#define M_   (B_ * S_)      // 8192
#define N3_  (3 * D_)       // 3072

#define GLDS16(g, l)                                                        \
  __builtin_amdgcn_global_load_lds(                                         \
      (const __attribute__((address_space(1))) void*)(g),                   \
      (__attribute__((address_space(3))) void*)(l), 16, 0, 0)

__device__ __forceinline__ unsigned pack_bf2(float a, float b) {
  union { __hip_bfloat16 h; unsigned short s; } ua, ub;
  ua.h = __float2bfloat16(a);
  ub.h = __float2bfloat16(b);
  return (unsigned)ua.s | ((unsigned)ub.s << 16);
}

__device__ __forceinline__ float bf_lo(unsigned u) {
  union { unsigned x; float f; } c; c.x = u << 16; return c.f;
}
__device__ __forceinline__ float bf_hi(unsigned u) {
  union { unsigned x; float f; } c; c.x = u & 0xffff0000u; return c.f;
}

// --------------------------------------------------------- fused prep ----
// R17: cast + both weight transposes in ONE launch (was 3 independent
// kernels -> 2 fewer inter-launch gaps).  Bodies bit-identical; 1-D grid,
// block ranges: [0,8192) cast, [8192,11264) w_qkv transpose, rest w_proj.
__global__ __launch_bounds__(256) void prep_fused(
    const float* __restrict__ x, __hip_bfloat16* __restrict__ xb,
    const float* __restrict__ w_qkv, __hip_bfloat16* __restrict__ wqkvT,
    const float* __restrict__ w_proj, __hip_bfloat16* __restrict__ wprojT) {
  __shared__ float tile[32][33];
  const int bid = blockIdx.x;
  const int t = threadIdx.x;

  if (bid < 8192) {                       // ---- cast x -> xb (bf16) ----
    int i = (bid * 256 + t) * 4;
    if (i + 3 < M_ * D_) {
      float4 v = *(const float4*)(x + i);
      union { ushort4 u4; __hip_bfloat16 h[4]; } p;
      p.h[0] = __float2bfloat16(v.x);
      p.h[1] = __float2bfloat16(v.y);
      p.h[2] = __float2bfloat16(v.z);
      p.h[3] = __float2bfloat16(v.w);
      *(ushort4*)(xb + i) = p.u4;
    }
    return;
  }

  // ---- transpose_cast: in[rows][cols] f32 -> out[cols][rows] bf16 ----
  const float* in;
  __hip_bfloat16* out;
  int rows, cols, bx, by;
  if (bid < 8192 + 3072) {                // w_qkv: rows=D_, cols=N3_
    const int tb = bid - 8192;
    in = w_qkv; out = wqkvT; rows = D_; cols = N3_;
    bx = (tb % (N3_ / 32)) * 32;
    by = (tb / (N3_ / 32)) * 32;
  } else {                                // w_proj: rows=D_, cols=D_
    const int tb = bid - (8192 + 3072);
    in = w_proj; out = wprojT; rows = D_; cols = D_;
    bx = (tb % (D_ / 32)) * 32;
    by = (tb / (D_ / 32)) * 32;
  }
  const int tx = t & 31, ty = t >> 5;     // (32, 8)
#pragma unroll
  for (int i = 0; i < 4; ++i)
    tile[ty + i * 8][tx] = in[(size_t)(by + ty + i * 8) * cols + bx + tx];
  __syncthreads();
#pragma unroll
  for (int i = 0; i < 4; ++i)
    out[(size_t)(bx + ty + i * 8) * rows + by + tx] =
        __float2bfloat16(tile[tx][ty + i * 8]);
}

// ----------------------------------------------------------------- GEMM ----
__device__ inline void store_out(float* p, float v) { *p = v; }
__device__ inline void store_out(__hip_bfloat16* p, float v) {
  *p = __float2bfloat16(v);
}

// XCD-chunked bijective block swizzle (nwg % 8 == 0 for both launches):
// id' = (id&7)*(nwg/8) + (id>>3) is a bijection on [0,nwg); same-A-panel
// blocks land on one XCD's L2.
template <typename OUT_T, bool WVT>
__global__ __launch_bounds__(256) void gemm_bt_bias(
    const __hip_bfloat16* __restrict__ A, const __hip_bfloat16* __restrict__ Bt,
    const float* __restrict__ bias, OUT_T* __restrict__ C,
    __hip_bfloat16* __restrict__ vt, int M, int N, int K) {
  __shared__ __align__(16) __hip_bfloat16 Alds[128 * 64];
  __shared__ __align__(16) __hip_bfloat16 Blds[128 * 64];
  const int t = threadIdx.x;
  const int wave = t >> 6, lane = t & 63;
  const int quad = lane >> 4, l15 = lane & 15;
  const int wm = (wave >> 1) * 64, wn = (wave & 1) * 64;

  const int gx = gridDim.x;
  const int nwg = gx * gridDim.y;
  int id = blockIdx.y * gx + blockIdx.x;
  id = (id & 7) * (nwg >> 3) + (id >> 3);     // bijective: nwg % 8 == 0
  const int m0 = (id / gx) * 128, n0 = (id % gx) * 128;

  const int rsub = lane >> 3;
  const int gc16 = (lane & 7) ^ (rsub & 7);
  const __hip_bfloat16* gA[4];
  const __hip_bfloat16* gB[4];
  __hip_bfloat16* lA[4];
  __hip_bfloat16* lB[4];
#pragma unroll
  for (int i = 0; i < 4; ++i) {
    int c = wave * 4 + i;
    int row = c * 8 + rsub;
    gA[i] = A + (size_t)(m0 + row) * K + gc16 * 8;
    gB[i] = Bt + (size_t)(n0 + row) * K + gc16 * 8;
    lA[i] = Alds + c * 512;
    lB[i] = Blds + c * 512;
  }

  f32x4 acc[4][4] = {};

  for (int k0 = 0; k0 < K; k0 += 64) {
#pragma unroll
    for (int i = 0; i < 4; ++i) {
      GLDS16(gA[i] + k0, lA[i]);
      GLDS16(gB[i] + k0, lB[i]);
    }
    __syncthreads();
#pragma unroll
    for (int kk = 0; kk < 2; ++kk) {
      const int fo = ((kk * 4 + quad) ^ (l15 & 7)) * 8;  // swizzled frag col
      short8 a[4], bfr[4];
#pragma unroll
      for (int mt = 0; mt < 4; ++mt)
        a[mt] = *(const short8*)(Alds + (wm + mt * 16 + l15) * 64 + fo);
#pragma unroll
      for (int nt = 0; nt < 4; ++nt)
        bfr[nt] = *(const short8*)(Blds + (wn + nt * 16 + l15) * 64 + fo);
#pragma unroll
      for (int mt = 0; mt < 4; ++mt)
#pragma unroll
        for (int nt = 0; nt < 4; ++nt)
          acc[mt][nt] = __builtin_amdgcn_mfma_f32_16x16x32_bf16(
              a[mt], bfr[nt], acc[mt][nt], 0, 0, 0);
    }
    __syncthreads();
  }

  if (WVT && n0 >= 2048) {
#pragma unroll
    for (int mt = 0; mt < 4; ++mt)
#pragma unroll
      for (int nt = 0; nt < 4; ++nt) {
        int col = n0 + wn + nt * 16 + l15;
        float bv = bias[col];
        int hv = (col - 2048) >> 6, d = (col - 2048) & 63;
        int row0 = m0 + wm + mt * 16 + quad * 4;
        int bidx = row0 >> 11, s = row0 & 2047;
        uint2 w;
        w.x = pack_bf2(acc[mt][nt][0] + bv, acc[mt][nt][1] + bv);
        w.y = pack_bf2(acc[mt][nt][2] + bv, acc[mt][nt][3] + bv);
        *(uint2*)(vt + ((size_t)(bidx * 16 + hv) * 64 + d) * 2048 + s) = w;
      }
  } else {
#pragma unroll
    for (int mt = 0; mt < 4; ++mt)
#pragma unroll
      for (int nt = 0; nt < 4; ++nt) {
        int col = n0 + wn + nt * 16 + l15;
        float bv = bias[col];
#pragma unroll
        for (int r = 0; r < 4; ++r) {
          int row = m0 + wm + mt * 16 + quad * 4 + r;
          store_out(C + (size_t)row * N + col, acc[mt][nt][r] + bv);
        }
      }
  }
}

// ------------------------------------------------------ flash attention ----
// R17 attn = byte-identical R16 (green, 80.8 us).  This round's single
// variable is kernel-count (prep merge); attn counters are the control.
__global__ __launch_bounds__(256, 4) void attn_causal(
    const __hip_bfloat16* __restrict__ qkv,
    const __hip_bfloat16* __restrict__ vt,
    __hip_bfloat16* __restrict__ ctx) {
  __shared__ __align__(16) __hip_bfloat16 Klds[2][64 * 64];  // [buf][kpos][d]
  __shared__ __align__(16) __hip_bfloat16 Vlds[2][64 * 64];  // [buf][d][kpos]

  const int t = threadIdx.x;
  const int wave = t >> 6, lane = t & 63;
  const int kh = wave >> 1, rh = wave & 1;     // kpos-half, row-half
  const int r31 = lane & 31, a5 = lane >> 5;
  const int xr = r31 & 7;                      // swizzle row phase

  // ---- XCD-pinned decode: all 16 xb-blocks of a (b,h) pair on one XCD ----
  const int wg = blockIdx.x;                  // 0..1023
  const int xcd = wg & 7, loc = wg >> 3;
  const int pair = (xcd << 3) | (loc >> 4);   // 8 pairs per XCD
  const int xb = loc & 15;
  const int b = pair >> 4, h = pair & 15;

  const size_t qbase = (size_t)b * S_ * N3_ + h * HD_;
  const size_t kbase = qbase + D_;
  const size_t vtbase = (size_t)(b * H_ + h) * HD_ * S_;
  const float C2 = 0.18033688f;  // (1/sqrt(64)) * log2(e)

  // ---- staging: pre-swizzled global source, linear LDS dest ----
  const int rsub = lane >> 3;               // row within 8-row subtile
  const int swz = ((lane & 7) ^ rsub) * 8;  // swizzled col (elements)
  const __hip_bfloat16* gK[2];              // tile-0 bases
  const __hip_bfloat16* gV[2];
  __hip_bfloat16* lK[2];
  __hip_bfloat16* lV[2];
#pragma unroll
  for (int i = 0; i < 2; ++i) {
    const int c = wave * 2 + i;             // subtile id (wave-uniform base)
    gK[i] = qkv + kbase + (size_t)(c * 8 + rsub) * N3_ + swz;
    gV[i] = vt + vtbase + (size_t)(c * 8 + rsub) * S_ + swz;
    lK[i] = &Klds[0][c * 512];
    lV[i] = &Vlds[0][c * 512];
  }

  // prologue: stage tile 0 -> buf 0
#pragma unroll
  for (int i = 0; i < 2; ++i) {
    GLDS16(gK[i], lK[i]);
    GLDS16(gV[i], lV[i]);
  }
  __syncthreads();
  int cur = 0;

// pack own p-pair dwords + same-qrow cross-half exchange -> PV B-fragment.
// R10-proven shfl_xor form.
#define MKFRAG(sv, Bofs, OUT)                                          \
  {                                                                    \
    unsigned dA0 = pack_bf2(sv[Bofs + 0], sv[Bofs + 1]);               \
    unsigned dA1 = pack_bf2(sv[Bofs + 2], sv[Bofs + 3]);               \
    unsigned dB0 = pack_bf2(sv[Bofs + 4], sv[Bofs + 5]);               \
    unsigned dB1 = pack_bf2(sv[Bofs + 6], sv[Bofs + 7]);               \
    unsigned c0 = (unsigned)__shfl_xor((int)(a5 ? dA0 : dB0), 32);     \
    unsigned c1 = (unsigned)__shfl_xor((int)(a5 ? dA1 : dB1), 32);     \
    union { unsigned u[4]; short8 s8; } pu;                            \
    pu.u[0] = a5 ? c0 : dA0;                                           \
    pu.u[1] = a5 ? c1 : dA1;                                           \
    pu.u[2] = a5 ? dB0 : c0;                                           \
    pu.u[3] = a5 ? dB1 : c1;                                           \
    OUT = pu.s8;                                                       \
  }

  for (int sel = 0; sel < 2; ++sel) {
    const int qb = sel ? 31 - xb : xb;
    const int qrow = qb * 64 + rh * 32 + r31;   // this lane's q-row

    // Q fragments: B-operand, k = a5*8+j within each 16-d chunk
    short8 qf[4];
#pragma unroll
    for (int dc = 0; dc < 4; ++dc)
      qf[dc] = *(const short8*)(qkv + qbase + (size_t)qrow * N3_ +
                                dc * 16 + a5 * 8);

    f32x16 o0 = {}, o1 = {};                  // O^T, d-halves 0-31 / 32-63
    float m_r = -1e30f, l_r = 0.f;

    for (int kb = 0; kb <= qb; ++kb) {
      // ---- prefetch next tile into buf[cur^1] (tile 0 at sel boundary) ----
      if (sel == 0 || kb < qb) {
        const size_t nk = (kb < qb) ? (size_t)(kb + 1) : 0;
        const size_t ko = nk * (size_t)(64 * N3_);
        const size_t vo = nk * 64;
        const int nb = (cur ^ 1) * 4096;
#pragma unroll
        for (int i = 0; i < 2; ++i) {
          GLDS16(gK[i] + ko, lK[i] + nb);
          GLDS16(gV[i] + vo, lV[i] + nb);
        }
      }

      const bool diag = (kb == qb);
      if (!(diag && kh == 1 && rh == 0)) {   // that wave is fully masked
        const __hip_bfloat16* Kb = &Klds[cur][0];
        const __hip_bfloat16* Vb = &Vlds[cur][0];

        // ---- K A-frags: row kpos = kh*32+r31 (swizzled b128) ----
        short8 kf[4];
#pragma unroll
        for (int dc = 0; dc < 4; ++dc)
          kf[dc] = *(const short8*)(Kb + (kh * 32 + r31) * 64 +
                                    (((dc * 2 + a5) ^ xr) * 8));

        // ---- QK^T: s[kpos-half][qrow] ----
        f32x16 s = {};
        __builtin_amdgcn_s_setprio(1);
#pragma unroll
        for (int dc = 0; dc < 4; ++dc)
          s = __builtin_amdgcn_mfma_f32_32x32x16_bf16(kf[dc], qf[dc], s,
                                                      0, 0, 0);
        __builtin_amdgcn_s_setprio(0);

        if (diag && kh == rh) {  // partial mask (kin > r31)
#pragma unroll
          for (int reg = 0; reg < 16; ++reg) {
            const int kin = (reg & 3) + 8 * (reg >> 2) + 4 * a5;
            if (kin > r31) s[reg] = -1e30f;
          }
        }

        // ---- row max: depth-4 tree + one cross-half exchange ----
        float t8[8];
#pragma unroll
        for (int i = 0; i < 8; ++i) t8[i] = fmaxf(s[i], s[i + 8]);
#pragma unroll
        for (int st = 4; st >= 1; st >>= 1)
#pragma unroll
          for (int i = 0; i < 4; ++i)
            if (i < st) t8[i] = fmaxf(t8[i], t8[i + st]);
        float tm = fmaxf(t8[0], __shfl_xor(t8[0], 32));
        const float pm = tm * C2;

        // defer-max: rescale only when the running max grew (P <= 2^8)
        if (!__all(pm - m_r <= 8.0f)) {
          const float mn = fmaxf(m_r, pm);
          const float al = __builtin_amdgcn_exp2f(m_r - mn);
          m_r = mn;
          l_r *= al;
          o0 *= al;
          o1 *= al;
        }
        const float mneg = -m_r;

        // ---- P = exp2(fma(s,C2,-m)) in place ----
#pragma unroll
        for (int reg = 0; reg < 16; ++reg)
          s[reg] = __builtin_amdgcn_exp2f(__builtin_fmaf(s[reg], C2, mneg));

        // ---- rowsum: in-lane f32 tree + cross-half add ----
        float u8[8];
#pragma unroll
        for (int i = 0; i < 8; ++i) u8[i] = s[i] + s[i + 8];
#pragma unroll
        for (int st = 4; st >= 1; st >>= 1)
#pragma unroll
          for (int i = 0; i < 4; ++i)
            if (i < st) u8[i] = u8[i] + u8[i + st];
        l_r += u8[0] + __shfl_xor(u8[0], 32);

        // ---- pack + exchange -> 2 PV B-fragments (16 kpos each) ----
        short8 pf[2];
        MKFRAG(s, 0, pf[0]);
        MKFRAG(s, 8, pf[1]);

        // ---- PV: A = V^T[d][kpos] frags, B = pf; accumulate O^T ----
        __builtin_amdgcn_s_setprio(1);
#pragma unroll
        for (int kc = 0; kc < 2; ++kc) {
          const int u = (((kh * 2 + kc) * 2 + a5) ^ xr) * 8;
          short8 v0 = *(const short8*)(Vb + r31 * 64 + u);
          short8 v1 = *(const short8*)(Vb + (32 + r31) * 64 + u);
          o0 = __builtin_amdgcn_mfma_f32_32x32x16_bf16(v0, pf[kc], o0,
                                                       0, 0, 0);
          o1 = __builtin_amdgcn_mfma_f32_32x32x16_bf16(v1, pf[kc], o1,
                                                       0, 0, 0);
        }
        __builtin_amdgcn_s_setprio(0);
      }

      __syncthreads();  // lands prefetch (vmcnt) + guards buf reuse
      cur ^= 1;
    }

    // ---- merge kh=1 partial into kh=0 via LDS scratch (= consumed buf) ----
    // O_b in bf16: Klds[cur^1] (64 rows x 128 B = exactly 8 KB).
    // m/l pairs: first 512 B of Vlds[cur^1] (fully free otherwise).
    {
      __hip_bfloat16* osb = &Klds[cur ^ 1][0];   // [q][d] bf16
      float* ml = (float*)&Vlds[cur ^ 1][0];     // [q][2]
      const int q = rh * 32 + r31;
      if (kh == 1) {
        if (a5 == 0) {
          ml[q * 2] = m_r;
          ml[q * 2 + 1] = l_r;
        }
        __hip_bfloat16* orow = osb + q * 64;
#pragma unroll
        for (int q2 = 0; q2 < 4; ++q2) {
          uint2 w;
          w.x = pack_bf2(o0[q2 * 4 + 0], o0[q2 * 4 + 1]);
          w.y = pack_bf2(o0[q2 * 4 + 2], o0[q2 * 4 + 3]);
          *(uint2*)(orow + 8 * q2 + 4 * a5) = w;
          w.x = pack_bf2(o1[q2 * 4 + 0], o1[q2 * 4 + 1]);
          w.y = pack_bf2(o1[q2 * 4 + 2], o1[q2 * 4 + 3]);
          *(uint2*)(orow + 32 + 8 * q2 + 4 * a5) = w;
        }
      }
      __syncthreads();
      if (kh == 0) {
        const float m_b = ml[q * 2];
        const float l_b = ml[q * 2 + 1];
        const float mn = fmaxf(m_r, m_b);
        const float aa = __builtin_amdgcn_exp2f(m_r - mn);
        const float ab = __builtin_amdgcn_exp2f(m_b - mn);
        const float lt = l_r * aa + l_b * ab;
        const float rl = __builtin_amdgcn_rcpf(lt);
        const float fa = aa * rl, fb = ab * rl;
        const __hip_bfloat16* orow = osb + q * 64;
        __hip_bfloat16* crow = ctx + ((size_t)b * S_ + qrow) * D_ + h * HD_;
#pragma unroll
        for (int q2 = 0; q2 < 4; ++q2) {
          uint2 v0 = *(const uint2*)(orow + 8 * q2 + 4 * a5);
          uint2 v1 = *(const uint2*)(orow + 32 + 8 * q2 + 4 * a5);
          uint2 w;
          w.x = pack_bf2(o0[q2 * 4 + 0] * fa + bf_lo(v0.x) * fb,
                         o0[q2 * 4 + 1] * fa + bf_hi(v0.x) * fb);
          w.y = pack_bf2(o0[q2 * 4 + 2] * fa + bf_lo(v0.y) * fb,
                         o0[q2 * 4 + 3] * fa + bf_hi(v0.y) * fb);
          *(uint2*)(crow + 8 * q2 + 4 * a5) = w;
          w.x = pack_bf2(o1[q2 * 4 + 0] * fa + bf_lo(v1.x) * fb,
                         o1[q2 * 4 + 1] * fa + bf_hi(v1.x) * fb);
          w.y = pack_bf2(o1[q2 * 4 + 2] * fa + bf_lo(v1.y) * fb,
                         o1[q2 * 4 + 3] * fa + bf_hi(v1.y) * fb);
          *(uint2*)(crow + 32 + 8 * q2 + 4 * a5) = w;
        }
      }
      __syncthreads();  // protect scratch from next sel's prefetch
    }
  }
#undef MKFRAG
}

// --------------------------------------------------------------- launch ----
extern "C" void kernel_launch(void* const* d_in, const int* in_sizes, int n_in,
                              void* d_out, int out_size, void* d_ws,
                              size_t ws_size, hipStream_t stream) {
  const float* x      = (const float*)d_in[0];
  const float* w_qkv  = (const float*)d_in[1];
  const float* b_qkv  = (const float*)d_in[2];
  const float* w_proj = (const float*)d_in[3];
  const float* b_proj = (const float*)d_in[4];
  float* out = (float*)d_out;

  char* ws = (char*)d_ws;
  __hip_bfloat16* xb     = (__hip_bfloat16*)(ws + 0);          // 16 MB
  __hip_bfloat16* wqkvT  = (__hip_bfloat16*)(ws + 16777216);   // 6 MB
  __hip_bfloat16* wprojT = (__hip_bfloat16*)(ws + 23068672);   // 2 MB
  __hip_bfloat16* qkvb   = (__hip_bfloat16*)(ws + 25165824);   // 50.3 MB
  __hip_bfloat16* ctx    = (__hip_bfloat16*)(ws + 75497472);   // 16 MB
  __hip_bfloat16* vt2    = (__hip_bfloat16*)(ws + 91750400);   // 16 MB

  // one fused prep launch: cast (8192 blocks) + wqkv T (3072) + wproj T (1024)
  prep_fused<<<8192 + 3072 + 1024, 256, 0, stream>>>(
      x, xb, w_qkv, wqkvT, w_proj, wprojT);

  gemm_bt_bias<__hip_bfloat16, true>
      <<<dim3(N3_ / 128, M_ / 128), 256, 0, stream>>>(
          xb, wqkvT, b_qkv, qkvb, vt2, M_, N3_, D_);

  attn_causal<<<1024, 256, 0, stream>>>(qkvb, vt2, ctx);

  gemm_bt_bias<float, false><<<dim3(D_ / 128, M_ / 128), 256, 0, stream>>>(
      ctx, wprojT, b_proj, out, (__hip_bfloat16*)nullptr, M_, D_, D_);
}

// Round 13
// 262.571 us; speedup vs baseline: 1.0235x; 1.0235x over previous
//
#include <hip/hip_runtime.h>
#include <hip/hip_bf16.h>

typedef __attribute__((ext_vector_type(8))) short short8;
typedef __attribute__((ext_vector_type(4))) float f32x4;
typedef __attribute__((ext_vector_type(16))) float f32x16;

#define B_   4
#define S_   2048
#define D_   1024
#define H_   16
#define HD_  64
#define M_   (B_ * S_)      // 8192
#define N3_  (3 * D_)       // 3072

#define GLDS16(g, l)                                                        \
  __builtin_amdgcn_global_load_lds(                                         \
      (const __attribute__((address_space(1))) void*)(g),                   \
      (__attribute__((address_space(3))) void*)(l), 16, 0, 0)

__device__ __forceinline__ unsigned pack_bf2(float a, float b) {
  union { __hip_bfloat16 h; unsigned short s; } ua, ub;
  ua.h = __float2bfloat16(a);
  ub.h = __float2bfloat16(b);
  return (unsigned)ua.s | ((unsigned)ub.s << 16);
}

__device__ __forceinline__ float bf_lo(unsigned u) {
  union { unsigned x; float f; } c; c.x = u << 16; return c.f;
}
__device__ __forceinline__ float bf_hi(unsigned u) {
  union { unsigned x; float f; } c; c.x = u & 0xffff0000u; return c.f;
}

// --------------------------------------------------------- fused prep ----
// cast + both weight transposes in ONE launch.  1-D grid, block ranges:
// [0,8192) cast, [8192,11264) w_qkv transpose, rest w_proj transpose.
__global__ __launch_bounds__(256) void prep_fused(
    const float* __restrict__ x, __hip_bfloat16* __restrict__ xb,
    const float* __restrict__ w_qkv, __hip_bfloat16* __restrict__ wqkvT,
    const float* __restrict__ w_proj, __hip_bfloat16* __restrict__ wprojT) {
  __shared__ float tile[32][33];
  const int bid = blockIdx.x;
  const int t = threadIdx.x;

  if (bid < 8192) {                       // ---- cast x -> xb (bf16) ----
    int i = (bid * 256 + t) * 4;
    if (i + 3 < M_ * D_) {
      float4 v = *(const float4*)(x + i);
      union { ushort4 u4; __hip_bfloat16 h[4]; } p;
      p.h[0] = __float2bfloat16(v.x);
      p.h[1] = __float2bfloat16(v.y);
      p.h[2] = __float2bfloat16(v.z);
      p.h[3] = __float2bfloat16(v.w);
      *(ushort4*)(xb + i) = p.u4;
    }
    return;
  }

  // ---- transpose_cast: in[rows][cols] f32 -> out[cols][rows] bf16 ----
  const float* in;
  __hip_bfloat16* out;
  int rows, cols, bx, by;
  if (bid < 8192 + 3072) {                // w_qkv: rows=D_, cols=N3_
    const int tb = bid - 8192;
    in = w_qkv; out = wqkvT; rows = D_; cols = N3_;
    bx = (tb % (N3_ / 32)) * 32;
    by = (tb / (N3_ / 32)) * 32;
  } else {                                // w_proj: rows=D_, cols=D_
    const int tb = bid - (8192 + 3072);
    in = w_proj; out = wprojT; rows = D_; cols = D_;
    bx = (tb % (D_ / 32)) * 32;
    by = (tb / (D_ / 32)) * 32;
  }
  const int tx = t & 31, ty = t >> 5;     // (32, 8)
#pragma unroll
  for (int i = 0; i < 4; ++i)
    tile[ty + i * 8][tx] = in[(size_t)(by + ty + i * 8) * cols + bx + tx];
  __syncthreads();
#pragma unroll
  for (int i = 0; i < 4; ++i)
    out[(size_t)(bx + ty + i * 8) * rows + by + tx] =
        __float2bfloat16(tile[tx][ty + i * 8]);
}

// ----------------------------------------------------------------- GEMM ----
__device__ inline void store_out(float* p, float v) { *p = v; }
__device__ inline void store_out(__hip_bfloat16* p, float v) {
  *p = __float2bfloat16(v);
}

// R18: tile-M parameterized (BM in {128, 64}).  G2 (M=8192,N=1024,K=1024)
// was grid-capped at 512 blocks = 2 blocks/CU -> ~215 TF (latency-bound,
// same disease attn had).  BM=64 doubles the grid to 1024 = 4/CU.
// XCD-chunked bijective block swizzle (nwg % 8 == 0 for all launches).
template <typename OUT_T, bool WVT, int BM>
__global__ __launch_bounds__(256) void gemm_bt_bias(
    const __hip_bfloat16* __restrict__ A, const __hip_bfloat16* __restrict__ Bt,
    const float* __restrict__ bias, OUT_T* __restrict__ C,
    __hip_bfloat16* __restrict__ vt, int M, int N, int K) {
  constexpr int MT = BM / 32;             // acc M-frags per wave
  __shared__ __align__(16) __hip_bfloat16 Alds[BM * 64];
  __shared__ __align__(16) __hip_bfloat16 Blds[128 * 64];
  const int t = threadIdx.x;
  const int wave = t >> 6, lane = t & 63;
  const int quad = lane >> 4, l15 = lane & 15;
  const int wm = (wave >> 1) * (BM / 2), wn = (wave & 1) * 64;

  const int gx = gridDim.x;
  const int nwg = gx * gridDim.y;
  int id = blockIdx.y * gx + blockIdx.x;
  id = (id & 7) * (nwg >> 3) + (id >> 3);     // bijective: nwg % 8 == 0
  const int m0 = (id / gx) * BM, n0 = (id % gx) * 128;

  const int rsub = lane >> 3;
  const int gc16 = (lane & 7) ^ (rsub & 7);
  const __hip_bfloat16* gA[MT];
  const __hip_bfloat16* gB[4];
  __hip_bfloat16* lA[MT];
  __hip_bfloat16* lB[4];
#pragma unroll
  for (int i = 0; i < MT; ++i) {          // A: BM/8 slots over 4 waves
    int c = wave * MT + i;
    gA[i] = A + (size_t)(m0 + c * 8 + rsub) * K + gc16 * 8;
    lA[i] = Alds + c * 512;
  }
#pragma unroll
  for (int i = 0; i < 4; ++i) {           // B: 16 slots over 4 waves
    int c = wave * 4 + i;
    gB[i] = Bt + (size_t)(n0 + c * 8 + rsub) * K + gc16 * 8;
    lB[i] = Blds + c * 512;
  }

  f32x4 acc[MT][4] = {};

  for (int k0 = 0; k0 < K; k0 += 64) {
#pragma unroll
    for (int i = 0; i < MT; ++i) GLDS16(gA[i] + k0, lA[i]);
#pragma unroll
    for (int i = 0; i < 4; ++i) GLDS16(gB[i] + k0, lB[i]);
    __syncthreads();
#pragma unroll
    for (int kk = 0; kk < 2; ++kk) {
      const int fo = ((kk * 4 + quad) ^ (l15 & 7)) * 8;  // swizzled frag col
      short8 a[MT], bfr[4];
#pragma unroll
      for (int mt = 0; mt < MT; ++mt)
        a[mt] = *(const short8*)(Alds + (wm + mt * 16 + l15) * 64 + fo);
#pragma unroll
      for (int nt = 0; nt < 4; ++nt)
        bfr[nt] = *(const short8*)(Blds + (wn + nt * 16 + l15) * 64 + fo);
#pragma unroll
      for (int mt = 0; mt < MT; ++mt)
#pragma unroll
        for (int nt = 0; nt < 4; ++nt)
          acc[mt][nt] = __builtin_amdgcn_mfma_f32_16x16x32_bf16(
              a[mt], bfr[nt], acc[mt][nt], 0, 0, 0);
    }
    __syncthreads();
  }

  if (WVT && n0 >= 2048) {
#pragma unroll
    for (int mt = 0; mt < MT; ++mt)
#pragma unroll
      for (int nt = 0; nt < 4; ++nt) {
        int col = n0 + wn + nt * 16 + l15;
        float bv = bias[col];
        int hv = (col - 2048) >> 6, d = (col - 2048) & 63;
        int row0 = m0 + wm + mt * 16 + quad * 4;
        int bidx = row0 >> 11, s = row0 & 2047;
        uint2 w;
        w.x = pack_bf2(acc[mt][nt][0] + bv, acc[mt][nt][1] + bv);
        w.y = pack_bf2(acc[mt][nt][2] + bv, acc[mt][nt][3] + bv);
        *(uint2*)(vt + ((size_t)(bidx * 16 + hv) * 64 + d) * 2048 + s) = w;
      }
  } else {
#pragma unroll
    for (int mt = 0; mt < MT; ++mt)
#pragma unroll
      for (int nt = 0; nt < 4; ++nt) {
        int col = n0 + wn + nt * 16 + l15;
        float bv = bias[col];
#pragma unroll
        for (int r = 0; r < 4; ++r) {
          int row = m0 + wm + mt * 16 + quad * 4 + r;
          store_out(C + (size_t)row * N + col, acc[mt][nt][r] + bv);
        }
      }
  }
}

// ------------------------------------------------------ flash attention ----
// Byte-identical R16/R17 attention (green, ~81-82 us) — control kernel.
__global__ __launch_bounds__(256, 4) void attn_causal(
    const __hip_bfloat16* __restrict__ qkv,
    const __hip_bfloat16* __restrict__ vt,
    __hip_bfloat16* __restrict__ ctx) {
  __shared__ __align__(16) __hip_bfloat16 Klds[2][64 * 64];  // [buf][kpos][d]
  __shared__ __align__(16) __hip_bfloat16 Vlds[2][64 * 64];  // [buf][d][kpos]

  const int t = threadIdx.x;
  const int wave = t >> 6, lane = t & 63;
  const int kh = wave >> 1, rh = wave & 1;     // kpos-half, row-half
  const int r31 = lane & 31, a5 = lane >> 5;
  const int xr = r31 & 7;                      // swizzle row phase

  // ---- XCD-pinned decode: all 16 xb-blocks of a (b,h) pair on one XCD ----
  const int wg = blockIdx.x;                  // 0..1023
  const int xcd = wg & 7, loc = wg >> 3;
  const int pair = (xcd << 3) | (loc >> 4);   // 8 pairs per XCD
  const int xb = loc & 15;
  const int b = pair >> 4, h = pair & 15;

  const size_t qbase = (size_t)b * S_ * N3_ + h * HD_;
  const size_t kbase = qbase + D_;
  const size_t vtbase = (size_t)(b * H_ + h) * HD_ * S_;
  const float C2 = 0.18033688f;  // (1/sqrt(64)) * log2(e)

  // ---- staging: pre-swizzled global source, linear LDS dest ----
  const int rsub = lane >> 3;               // row within 8-row subtile
  const int swz = ((lane & 7) ^ rsub) * 8;  // swizzled col (elements)
  const __hip_bfloat16* gK[2];              // tile-0 bases
  const __hip_bfloat16* gV[2];
  __hip_bfloat16* lK[2];
  __hip_bfloat16* lV[2];
#pragma unroll
  for (int i = 0; i < 2; ++i) {
    const int c = wave * 2 + i;             // subtile id (wave-uniform base)
    gK[i] = qkv + kbase + (size_t)(c * 8 + rsub) * N3_ + swz;
    gV[i] = vt + vtbase + (size_t)(c * 8 + rsub) * S_ + swz;
    lK[i] = &Klds[0][c * 512];
    lV[i] = &Vlds[0][c * 512];
  }

  // prologue: stage tile 0 -> buf 0
#pragma unroll
  for (int i = 0; i < 2; ++i) {
    GLDS16(gK[i], lK[i]);
    GLDS16(gV[i], lV[i]);
  }
  __syncthreads();
  int cur = 0;

// pack own p-pair dwords + same-qrow cross-half exchange -> PV B-fragment.
// R10-proven shfl_xor form.
#define MKFRAG(sv, Bofs, OUT)                                          \
  {                                                                    \
    unsigned dA0 = pack_bf2(sv[Bofs + 0], sv[Bofs + 1]);               \
    unsigned dA1 = pack_bf2(sv[Bofs + 2], sv[Bofs + 3]);               \
    unsigned dB0 = pack_bf2(sv[Bofs + 4], sv[Bofs + 5]);               \
    unsigned dB1 = pack_bf2(sv[Bofs + 6], sv[Bofs + 7]);               \
    unsigned c0 = (unsigned)__shfl_xor((int)(a5 ? dA0 : dB0), 32);     \
    unsigned c1 = (unsigned)__shfl_xor((int)(a5 ? dA1 : dB1), 32);     \
    union { unsigned u[4]; short8 s8; } pu;                            \
    pu.u[0] = a5 ? c0 : dA0;                                           \
    pu.u[1] = a5 ? c1 : dA1;                                           \
    pu.u[2] = a5 ? dB0 : c0;                                           \
    pu.u[3] = a5 ? dB1 : c1;                                           \
    OUT = pu.s8;                                                       \
  }

  for (int sel = 0; sel < 2; ++sel) {
    const int qb = sel ? 31 - xb : xb;
    const int qrow = qb * 64 + rh * 32 + r31;   // this lane's q-row

    // Q fragments: B-operand, k = a5*8+j within each 16-d chunk
    short8 qf[4];
#pragma unroll
    for (int dc = 0; dc < 4; ++dc)
      qf[dc] = *(const short8*)(qkv + qbase + (size_t)qrow * N3_ +
                                dc * 16 + a5 * 8);

    f32x16 o0 = {}, o1 = {};                  // O^T, d-halves 0-31 / 32-63
    float m_r = -1e30f, l_r = 0.f;

    for (int kb = 0; kb <= qb; ++kb) {
      // ---- prefetch next tile into buf[cur^1] (tile 0 at sel boundary) ----
      if (sel == 0 || kb < qb) {
        const size_t nk = (kb < qb) ? (size_t)(kb + 1) : 0;
        const size_t ko = nk * (size_t)(64 * N3_);
        const size_t vo = nk * 64;
        const int nb = (cur ^ 1) * 4096;
#pragma unroll
        for (int i = 0; i < 2; ++i) {
          GLDS16(gK[i] + ko, lK[i] + nb);
          GLDS16(gV[i] + vo, lV[i] + nb);
        }
      }

      const bool diag = (kb == qb);
      if (!(diag && kh == 1 && rh == 0)) {   // that wave is fully masked
        const __hip_bfloat16* Kb = &Klds[cur][0];
        const __hip_bfloat16* Vb = &Vlds[cur][0];

        // ---- K A-frags: row kpos = kh*32+r31 (swizzled b128) ----
        short8 kf[4];
#pragma unroll
        for (int dc = 0; dc < 4; ++dc)
          kf[dc] = *(const short8*)(Kb + (kh * 32 + r31) * 64 +
                                    (((dc * 2 + a5) ^ xr) * 8));

        // ---- QK^T: s[kpos-half][qrow] ----
        f32x16 s = {};
        __builtin_amdgcn_s_setprio(1);
#pragma unroll
        for (int dc = 0; dc < 4; ++dc)
          s = __builtin_amdgcn_mfma_f32_32x32x16_bf16(kf[dc], qf[dc], s,
                                                      0, 0, 0);
        __builtin_amdgcn_s_setprio(0);

        if (diag && kh == rh) {  // partial mask (kin > r31)
#pragma unroll
          for (int reg = 0; reg < 16; ++reg) {
            const int kin = (reg & 3) + 8 * (reg >> 2) + 4 * a5;
            if (kin > r31) s[reg] = -1e30f;
          }
        }

        // ---- row max: depth-4 tree + one cross-half exchange ----
        float t8[8];
#pragma unroll
        for (int i = 0; i < 8; ++i) t8[i] = fmaxf(s[i], s[i + 8]);
#pragma unroll
        for (int st = 4; st >= 1; st >>= 1)
#pragma unroll
          for (int i = 0; i < 4; ++i)
            if (i < st) t8[i] = fmaxf(t8[i], t8[i + st]);
        float tm = fmaxf(t8[0], __shfl_xor(t8[0], 32));
        const float pm = tm * C2;

        // defer-max: rescale only when the running max grew (P <= 2^8)
        if (!__all(pm - m_r <= 8.0f)) {
          const float mn = fmaxf(m_r, pm);
          const float al = __builtin_amdgcn_exp2f(m_r - mn);
          m_r = mn;
          l_r *= al;
          o0 *= al;
          o1 *= al;
        }
        const float mneg = -m_r;

        // ---- P = exp2(fma(s,C2,-m)) in place ----
#pragma unroll
        for (int reg = 0; reg < 16; ++reg)
          s[reg] = __builtin_amdgcn_exp2f(__builtin_fmaf(s[reg], C2, mneg));

        // ---- rowsum: in-lane f32 tree + cross-half add ----
        float u8[8];
#pragma unroll
        for (int i = 0; i < 8; ++i) u8[i] = s[i] + s[i + 8];
#pragma unroll
        for (int st = 4; st >= 1; st >>= 1)
#pragma unroll
          for (int i = 0; i < 4; ++i)
            if (i < st) u8[i] = u8[i] + u8[i + st];
        l_r += u8[0] + __shfl_xor(u8[0], 32);

        // ---- pack + exchange -> 2 PV B-fragments (16 kpos each) ----
        short8 pf[2];
        MKFRAG(s, 0, pf[0]);
        MKFRAG(s, 8, pf[1]);

        // ---- PV: A = V^T[d][kpos] frags, B = pf; accumulate O^T ----
        __builtin_amdgcn_s_setprio(1);
#pragma unroll
        for (int kc = 0; kc < 2; ++kc) {
          const int u = (((kh * 2 + kc) * 2 + a5) ^ xr) * 8;
          short8 v0 = *(const short8*)(Vb + r31 * 64 + u);
          short8 v1 = *(const short8*)(Vb + (32 + r31) * 64 + u);
          o0 = __builtin_amdgcn_mfma_f32_32x32x16_bf16(v0, pf[kc], o0,
                                                       0, 0, 0);
          o1 = __builtin_amdgcn_mfma_f32_32x32x16_bf16(v1, pf[kc], o1,
                                                       0, 0, 0);
        }
        __builtin_amdgcn_s_setprio(0);
      }

      __syncthreads();  // lands prefetch (vmcnt) + guards buf reuse
      cur ^= 1;
    }

    // ---- merge kh=1 partial into kh=0 via LDS scratch (= consumed buf) ----
    // O_b in bf16: Klds[cur^1] (64 rows x 128 B = exactly 8 KB).
    // m/l pairs: first 512 B of Vlds[cur^1] (fully free otherwise).
    {
      __hip_bfloat16* osb = &Klds[cur ^ 1][0];   // [q][d] bf16
      float* ml = (float*)&Vlds[cur ^ 1][0];     // [q][2]
      const int q = rh * 32 + r31;
      if (kh == 1) {
        if (a5 == 0) {
          ml[q * 2] = m_r;
          ml[q * 2 + 1] = l_r;
        }
        __hip_bfloat16* orow = osb + q * 64;
#pragma unroll
        for (int q2 = 0; q2 < 4; ++q2) {
          uint2 w;
          w.x = pack_bf2(o0[q2 * 4 + 0], o0[q2 * 4 + 1]);
          w.y = pack_bf2(o0[q2 * 4 + 2], o0[q2 * 4 + 3]);
          *(uint2*)(orow + 8 * q2 + 4 * a5) = w;
          w.x = pack_bf2(o1[q2 * 4 + 0], o1[q2 * 4 + 1]);
          w.y = pack_bf2(o1[q2 * 4 + 2], o1[q2 * 4 + 3]);
          *(uint2*)(orow + 32 + 8 * q2 + 4 * a5) = w;
        }
      }
      __syncthreads();
      if (kh == 0) {
        const float m_b = ml[q * 2];
        const float l_b = ml[q * 2 + 1];
        const float mn = fmaxf(m_r, m_b);
        const float aa = __builtin_amdgcn_exp2f(m_r - mn);
        const float ab = __builtin_amdgcn_exp2f(m_b - mn);
        const float lt = l_r * aa + l_b * ab;
        const float rl = __builtin_amdgcn_rcpf(lt);
        const float fa = aa * rl, fb = ab * rl;
        const __hip_bfloat16* orow = osb + q * 64;
        __hip_bfloat16* crow = ctx + ((size_t)b * S_ + qrow) * D_ + h * HD_;
#pragma unroll
        for (int q2 = 0; q2 < 4; ++q2) {
          uint2 v0 = *(const uint2*)(orow + 8 * q2 + 4 * a5);
          uint2 v1 = *(const uint2*)(orow + 32 + 8 * q2 + 4 * a5);
          uint2 w;
          w.x = pack_bf2(o0[q2 * 4 + 0] * fa + bf_lo(v0.x) * fb,
                         o0[q2 * 4 + 1] * fa + bf_hi(v0.x) * fb);
          w.y = pack_bf2(o0[q2 * 4 + 2] * fa + bf_lo(v0.y) * fb,
                         o0[q2 * 4 + 3] * fa + bf_hi(v0.y) * fb);
          *(uint2*)(crow + 8 * q2 + 4 * a5) = w;
          w.x = pack_bf2(o1[q2 * 4 + 0] * fa + bf_lo(v1.x) * fb,
                         o1[q2 * 4 + 1] * fa + bf_hi(v1.x) * fb);
          w.y = pack_bf2(o1[q2 * 4 + 2] * fa + bf_lo(v1.y) * fb,
                         o1[q2 * 4 + 3] * fa + bf_hi(v1.y) * fb);
          *(uint2*)(crow + 32 + 8 * q2 + 4 * a5) = w;
        }
      }
      __syncthreads();  // protect scratch from next sel's prefetch
    }
  }
#undef MKFRAG
}

// --------------------------------------------------------------- launch ----
extern "C" void kernel_launch(void* const* d_in, const int* in_sizes, int n_in,
                              void* d_out, int out_size, void* d_ws,
                              size_t ws_size, hipStream_t stream) {
  const float* x      = (const float*)d_in[0];
  const float* w_qkv  = (const float*)d_in[1];
  const float* b_qkv  = (const float*)d_in[2];
  const float* w_proj = (const float*)d_in[3];
  const float* b_proj = (const float*)d_in[4];
  float* out = (float*)d_out;

  char* ws = (char*)d_ws;
  __hip_bfloat16* xb     = (__hip_bfloat16*)(ws + 0);          // 16 MB
  __hip_bfloat16* wqkvT  = (__hip_bfloat16*)(ws + 16777216);   // 6 MB
  __hip_bfloat16* wprojT = (__hip_bfloat16*)(ws + 23068672);   // 2 MB
  __hip_bfloat16* qkvb   = (__hip_bfloat16*)(ws + 25165824);   // 50.3 MB
  __hip_bfloat16* ctx    = (__hip_bfloat16*)(ws + 75497472);   // 16 MB
  __hip_bfloat16* vt2    = (__hip_bfloat16*)(ws + 91750400);   // 16 MB

  // one fused prep launch: cast (8192 blocks) + wqkv T (3072) + wproj T (1024)
  prep_fused<<<8192 + 3072 + 1024, 256, 0, stream>>>(
      x, xb, w_qkv, wqkvT, w_proj, wprojT);

  gemm_bt_bias<__hip_bfloat16, true, 128>
      <<<dim3(N3_ / 128, M_ / 128), 256, 0, stream>>>(
          xb, wqkvT, b_qkv, qkvb, vt2, M_, N3_, D_);

  attn_causal<<<1024, 256, 0, stream>>>(qkvb, vt2, ctx);

  // G2 with BM=64: grid 8 x 128 = 1024 blocks = 4 blocks/CU (was 2)
  gemm_bt_bias<float, false, 64>
      <<<dim3(D_ / 128, M_ / 64), 256, 0, stream>>>(
          ctx, wprojT, b_proj, out, (__hip_bfloat16*)nullptr, M_, D_, D_);
}

// Round 14
// 248.099 us; speedup vs baseline: 1.0832x; 1.0583x over previous
//
#include <hip/hip_runtime.h>
#include <hip/hip_bf16.h>

typedef __attribute__((ext_vector_type(8))) short short8;
typedef __attribute__((ext_vector_type(4))) float f32x4;
typedef __attribute__((ext_vector_type(16))) float f32x16;

#define B_   4
#define S_   2048
#define D_   1024
#define H_   16
#define HD_  64
#define M_   (B_ * S_)      // 8192
#define N3_  (3 * D_)       // 3072

#define GLDS16(g, l)                                                        \
  __builtin_amdgcn_global_load_lds(                                         \
      (const __attribute__((address_space(1))) void*)(g),                   \
      (__attribute__((address_space(3))) void*)(l), 16, 0, 0)

__device__ __forceinline__ unsigned pack_bf2(float a, float b) {
  union { __hip_bfloat16 h; unsigned short s; } ua, ub;
  ua.h = __float2bfloat16(a);
  ub.h = __float2bfloat16(b);
  return (unsigned)ua.s | ((unsigned)ub.s << 16);
}

__device__ __forceinline__ float bf_lo(unsigned u) {
  union { unsigned x; float f; } c; c.x = u << 16; return c.f;
}
__device__ __forceinline__ float bf_hi(unsigned u) {
  union { unsigned x; float f; } c; c.x = u & 0xffff0000u; return c.f;
}

// --------------------------------------------------------- fused prep ----
// cast + both weight transposes in ONE launch.  1-D grid, block ranges:
// [0,8192) cast, [8192,11264) w_qkv transpose, rest w_proj transpose.
__global__ __launch_bounds__(256) void prep_fused(
    const float* __restrict__ x, __hip_bfloat16* __restrict__ xb,
    const float* __restrict__ w_qkv, __hip_bfloat16* __restrict__ wqkvT,
    const float* __restrict__ w_proj, __hip_bfloat16* __restrict__ wprojT) {
  __shared__ float tile[32][33];
  const int bid = blockIdx.x;
  const int t = threadIdx.x;

  if (bid < 8192) {                       // ---- cast x -> xb (bf16) ----
    int i = (bid * 256 + t) * 4;
    if (i + 3 < M_ * D_) {
      float4 v = *(const float4*)(x + i);
      union { ushort4 u4; __hip_bfloat16 h[4]; } p;
      p.h[0] = __float2bfloat16(v.x);
      p.h[1] = __float2bfloat16(v.y);
      p.h[2] = __float2bfloat16(v.z);
      p.h[3] = __float2bfloat16(v.w);
      *(ushort4*)(xb + i) = p.u4;
    }
    return;
  }

  // ---- transpose_cast: in[rows][cols] f32 -> out[cols][rows] bf16 ----
  const float* in;
  __hip_bfloat16* out;
  int rows, cols, bx, by;
  if (bid < 8192 + 3072) {                // w_qkv: rows=D_, cols=N3_
    const int tb = bid - 8192;
    in = w_qkv; out = wqkvT; rows = D_; cols = N3_;
    bx = (tb % (N3_ / 32)) * 32;
    by = (tb / (N3_ / 32)) * 32;
  } else {                                // w_proj: rows=D_, cols=D_
    const int tb = bid - (8192 + 3072);
    in = w_proj; out = wprojT; rows = D_; cols = D_;
    bx = (tb % (D_ / 32)) * 32;
    by = (tb / (D_ / 32)) * 32;
  }
  const int tx = t & 31, ty = t >> 5;     // (32, 8)
#pragma unroll
  for (int i = 0; i < 4; ++i)
    tile[ty + i * 8][tx] = in[(size_t)(by + ty + i * 8) * cols + bx + tx];
  __syncthreads();
#pragma unroll
  for (int i = 0; i < 4; ++i)
    out[(size_t)(bx + ty + i * 8) * rows + by + tx] =
        __float2bfloat16(tile[tx][ty + i * 8]);
}

// ----------------------------------------------------------------- GEMM ----
__device__ inline void store_out(float* p, float v) { *p = v; }
__device__ inline void store_out(__hip_bfloat16* p, float v) {
  *p = __float2bfloat16(v);
}

// Tile-M parameterized (BM in {128, 64}).  R19: __launch_bounds__(256, 4)
// caps VGPR at 128 -> 4 blocks/CU (was ~164 VGPR -> 3).  LDS (32 KB) allows
// 5; registers were the binding constraint.  Register arithmetic: acc 64 +
// frags 32 + addressing ~30 ~= 130, borderline -- if it spills, FETCH bump
// (R15 signature) will show and this reverts.
// XCD-chunked bijective block swizzle (nwg % 8 == 0 for all launches).
template <typename OUT_T, bool WVT, int BM>
__global__ __launch_bounds__(256, 4) void gemm_bt_bias(
    const __hip_bfloat16* __restrict__ A, const __hip_bfloat16* __restrict__ Bt,
    const float* __restrict__ bias, OUT_T* __restrict__ C,
    __hip_bfloat16* __restrict__ vt, int M, int N, int K) {
  constexpr int MT = BM / 32;             // acc M-frags per wave
  __shared__ __align__(16) __hip_bfloat16 Alds[BM * 64];
  __shared__ __align__(16) __hip_bfloat16 Blds[128 * 64];
  const int t = threadIdx.x;
  const int wave = t >> 6, lane = t & 63;
  const int quad = lane >> 4, l15 = lane & 15;
  const int wm = (wave >> 1) * (BM / 2), wn = (wave & 1) * 64;

  const int gx = gridDim.x;
  const int nwg = gx * gridDim.y;
  int id = blockIdx.y * gx + blockIdx.x;
  id = (id & 7) * (nwg >> 3) + (id >> 3);     // bijective: nwg % 8 == 0
  const int m0 = (id / gx) * BM, n0 = (id % gx) * 128;

  const int rsub = lane >> 3;
  const int gc16 = (lane & 7) ^ (rsub & 7);
  const __hip_bfloat16* gA[MT];
  const __hip_bfloat16* gB[4];
  __hip_bfloat16* lA[MT];
  __hip_bfloat16* lB[4];
#pragma unroll
  for (int i = 0; i < MT; ++i) {          // A: BM/8 slots over 4 waves
    int c = wave * MT + i;
    gA[i] = A + (size_t)(m0 + c * 8 + rsub) * K + gc16 * 8;
    lA[i] = Alds + c * 512;
  }
#pragma unroll
  for (int i = 0; i < 4; ++i) {           // B: 16 slots over 4 waves
    int c = wave * 4 + i;
    gB[i] = Bt + (size_t)(n0 + c * 8 + rsub) * K + gc16 * 8;
    lB[i] = Blds + c * 512;
  }

  f32x4 acc[MT][4] = {};

  for (int k0 = 0; k0 < K; k0 += 64) {
#pragma unroll
    for (int i = 0; i < MT; ++i) GLDS16(gA[i] + k0, lA[i]);
#pragma unroll
    for (int i = 0; i < 4; ++i) GLDS16(gB[i] + k0, lB[i]);
    __syncthreads();
#pragma unroll
    for (int kk = 0; kk < 2; ++kk) {
      const int fo = ((kk * 4 + quad) ^ (l15 & 7)) * 8;  // swizzled frag col
      short8 a[MT], bfr[4];
#pragma unroll
      for (int mt = 0; mt < MT; ++mt)
        a[mt] = *(const short8*)(Alds + (wm + mt * 16 + l15) * 64 + fo);
#pragma unroll
      for (int nt = 0; nt < 4; ++nt)
        bfr[nt] = *(const short8*)(Blds + (wn + nt * 16 + l15) * 64 + fo);
#pragma unroll
      for (int mt = 0; mt < MT; ++mt)
#pragma unroll
        for (int nt = 0; nt < 4; ++nt)
          acc[mt][nt] = __builtin_amdgcn_mfma_f32_16x16x32_bf16(
              a[mt], bfr[nt], acc[mt][nt], 0, 0, 0);
    }
    __syncthreads();
  }

  if (WVT && n0 >= 2048) {
#pragma unroll
    for (int mt = 0; mt < MT; ++mt)
#pragma unroll
      for (int nt = 0; nt < 4; ++nt) {
        int col = n0 + wn + nt * 16 + l15;
        float bv = bias[col];
        int hv = (col - 2048) >> 6, d = (col - 2048) & 63;
        int row0 = m0 + wm + mt * 16 + quad * 4;
        int bidx = row0 >> 11, s = row0 & 2047;
        uint2 w;
        w.x = pack_bf2(acc[mt][nt][0] + bv, acc[mt][nt][1] + bv);
        w.y = pack_bf2(acc[mt][nt][2] + bv, acc[mt][nt][3] + bv);
        *(uint2*)(vt + ((size_t)(bidx * 16 + hv) * 64 + d) * 2048 + s) = w;
      }
  } else {
#pragma unroll
    for (int mt = 0; mt < MT; ++mt)
#pragma unroll
      for (int nt = 0; nt < 4; ++nt) {
        int col = n0 + wn + nt * 16 + l15;
        float bv = bias[col];
#pragma unroll
        for (int r = 0; r < 4; ++r) {
          int row = m0 + wm + mt * 16 + quad * 4 + r;
          store_out(C + (size_t)row * N + col, acc[mt][nt][r] + bv);
        }
      }
  }
}

// ------------------------------------------------------ flash attention ----
// Byte-identical R16/R17/R18 attention (green, ~82 us) — control kernel.
__global__ __launch_bounds__(256, 4) void attn_causal(
    const __hip_bfloat16* __restrict__ qkv,
    const __hip_bfloat16* __restrict__ vt,
    __hip_bfloat16* __restrict__ ctx) {
  __shared__ __align__(16) __hip_bfloat16 Klds[2][64 * 64];  // [buf][kpos][d]
  __shared__ __align__(16) __hip_bfloat16 Vlds[2][64 * 64];  // [buf][d][kpos]

  const int t = threadIdx.x;
  const int wave = t >> 6, lane = t & 63;
  const int kh = wave >> 1, rh = wave & 1;     // kpos-half, row-half
  const int r31 = lane & 31, a5 = lane >> 5;
  const int xr = r31 & 7;                      // swizzle row phase

  // ---- XCD-pinned decode: all 16 xb-blocks of a (b,h) pair on one XCD ----
  const int wg = blockIdx.x;                  // 0..1023
  const int xcd = wg & 7, loc = wg >> 3;
  const int pair = (xcd << 3) | (loc >> 4);   // 8 pairs per XCD
  const int xb = loc & 15;
  const int b = pair >> 4, h = pair & 15;

  const size_t qbase = (size_t)b * S_ * N3_ + h * HD_;
  const size_t kbase = qbase + D_;
  const size_t vtbase = (size_t)(b * H_ + h) * HD_ * S_;
  const float C2 = 0.18033688f;  // (1/sqrt(64)) * log2(e)

  // ---- staging: pre-swizzled global source, linear LDS dest ----
  const int rsub = lane >> 3;               // row within 8-row subtile
  const int swz = ((lane & 7) ^ rsub) * 8;  // swizzled col (elements)
  const __hip_bfloat16* gK[2];              // tile-0 bases
  const __hip_bfloat16* gV[2];
  __hip_bfloat16* lK[2];
  __hip_bfloat16* lV[2];
#pragma unroll
  for (int i = 0; i < 2; ++i) {
    const int c = wave * 2 + i;             // subtile id (wave-uniform base)
    gK[i] = qkv + kbase + (size_t)(c * 8 + rsub) * N3_ + swz;
    gV[i] = vt + vtbase + (size_t)(c * 8 + rsub) * S_ + swz;
    lK[i] = &Klds[0][c * 512];
    lV[i] = &Vlds[0][c * 512];
  }

  // prologue: stage tile 0 -> buf 0
#pragma unroll
  for (int i = 0; i < 2; ++i) {
    GLDS16(gK[i], lK[i]);
    GLDS16(gV[i], lV[i]);
  }
  __syncthreads();
  int cur = 0;

// pack own p-pair dwords + same-qrow cross-half exchange -> PV B-fragment.
// R10-proven shfl_xor form.
#define MKFRAG(sv, Bofs, OUT)                                          \
  {                                                                    \
    unsigned dA0 = pack_bf2(sv[Bofs + 0], sv[Bofs + 1]);               \
    unsigned dA1 = pack_bf2(sv[Bofs + 2], sv[Bofs + 3]);               \
    unsigned dB0 = pack_bf2(sv[Bofs + 4], sv[Bofs + 5]);               \
    unsigned dB1 = pack_bf2(sv[Bofs + 6], sv[Bofs + 7]);               \
    unsigned c0 = (unsigned)__shfl_xor((int)(a5 ? dA0 : dB0), 32);     \
    unsigned c1 = (unsigned)__shfl_xor((int)(a5 ? dA1 : dB1), 32);     \
    union { unsigned u[4]; short8 s8; } pu;                            \
    pu.u[0] = a5 ? c0 : dA0;                                           \
    pu.u[1] = a5 ? c1 : dA1;                                           \
    pu.u[2] = a5 ? dB0 : c0;                                           \
    pu.u[3] = a5 ? dB1 : c1;                                           \
    OUT = pu.s8;                                                       \
  }

  for (int sel = 0; sel < 2; ++sel) {
    const int qb = sel ? 31 - xb : xb;
    const int qrow = qb * 64 + rh * 32 + r31;   // this lane's q-row

    // Q fragments: B-operand, k = a5*8+j within each 16-d chunk
    short8 qf[4];
#pragma unroll
    for (int dc = 0; dc < 4; ++dc)
      qf[dc] = *(const short8*)(qkv + qbase + (size_t)qrow * N3_ +
                                dc * 16 + a5 * 8);

    f32x16 o0 = {}, o1 = {};                  // O^T, d-halves 0-31 / 32-63
    float m_r = -1e30f, l_r = 0.f;

    for (int kb = 0; kb <= qb; ++kb) {
      // ---- prefetch next tile into buf[cur^1] (tile 0 at sel boundary) ----
      if (sel == 0 || kb < qb) {
        const size_t nk = (kb < qb) ? (size_t)(kb + 1) : 0;
        const size_t ko = nk * (size_t)(64 * N3_);
        const size_t vo = nk * 64;
        const int nb = (cur ^ 1) * 4096;
#pragma unroll
        for (int i = 0; i < 2; ++i) {
          GLDS16(gK[i] + ko, lK[i] + nb);
          GLDS16(gV[i] + vo, lV[i] + nb);
        }
      }

      const bool diag = (kb == qb);
      if (!(diag && kh == 1 && rh == 0)) {   // that wave is fully masked
        const __hip_bfloat16* Kb = &Klds[cur][0];
        const __hip_bfloat16* Vb = &Vlds[cur][0];

        // ---- K A-frags: row kpos = kh*32+r31 (swizzled b128) ----
        short8 kf[4];
#pragma unroll
        for (int dc = 0; dc < 4; ++dc)
          kf[dc] = *(const short8*)(Kb + (kh * 32 + r31) * 64 +
                                    (((dc * 2 + a5) ^ xr) * 8));

        // ---- QK^T: s[kpos-half][qrow] ----
        f32x16 s = {};
        __builtin_amdgcn_s_setprio(1);
#pragma unroll
        for (int dc = 0; dc < 4; ++dc)
          s = __builtin_amdgcn_mfma_f32_32x32x16_bf16(kf[dc], qf[dc], s,
                                                      0, 0, 0);
        __builtin_amdgcn_s_setprio(0);

        if (diag && kh == rh) {  // partial mask (kin > r31)
#pragma unroll
          for (int reg = 0; reg < 16; ++reg) {
            const int kin = (reg & 3) + 8 * (reg >> 2) + 4 * a5;
            if (kin > r31) s[reg] = -1e30f;
          }
        }

        // ---- row max: depth-4 tree + one cross-half exchange ----
        float t8[8];
#pragma unroll
        for (int i = 0; i < 8; ++i) t8[i] = fmaxf(s[i], s[i + 8]);
#pragma unroll
        for (int st = 4; st >= 1; st >>= 1)
#pragma unroll
          for (int i = 0; i < 4; ++i)
            if (i < st) t8[i] = fmaxf(t8[i], t8[i + st]);
        float tm = fmaxf(t8[0], __shfl_xor(t8[0], 32));
        const float pm = tm * C2;

        // defer-max: rescale only when the running max grew (P <= 2^8)
        if (!__all(pm - m_r <= 8.0f)) {
          const float mn = fmaxf(m_r, pm);
          const float al = __builtin_amdgcn_exp2f(m_r - mn);
          m_r = mn;
          l_r *= al;
          o0 *= al;
          o1 *= al;
        }
        const float mneg = -m_r;

        // ---- P = exp2(fma(s,C2,-m)) in place ----
#pragma unroll
        for (int reg = 0; reg < 16; ++reg)
          s[reg] = __builtin_amdgcn_exp2f(__builtin_fmaf(s[reg], C2, mneg));

        // ---- rowsum: in-lane f32 tree + cross-half add ----
        float u8[8];
#pragma unroll
        for (int i = 0; i < 8; ++i) u8[i] = s[i] + s[i + 8];
#pragma unroll
        for (int st = 4; st >= 1; st >>= 1)
#pragma unroll
          for (int i = 0; i < 4; ++i)
            if (i < st) u8[i] = u8[i] + u8[i + st];
        l_r += u8[0] + __shfl_xor(u8[0], 32);

        // ---- pack + exchange -> 2 PV B-fragments (16 kpos each) ----
        short8 pf[2];
        MKFRAG(s, 0, pf[0]);
        MKFRAG(s, 8, pf[1]);

        // ---- PV: A = V^T[d][kpos] frags, B = pf; accumulate O^T ----
        __builtin_amdgcn_s_setprio(1);
#pragma unroll
        for (int kc = 0; kc < 2; ++kc) {
          const int u = (((kh * 2 + kc) * 2 + a5) ^ xr) * 8;
          short8 v0 = *(const short8*)(Vb + r31 * 64 + u);
          short8 v1 = *(const short8*)(Vb + (32 + r31) * 64 + u);
          o0 = __builtin_amdgcn_mfma_f32_32x32x16_bf16(v0, pf[kc], o0,
                                                       0, 0, 0);
          o1 = __builtin_amdgcn_mfma_f32_32x32x16_bf16(v1, pf[kc], o1,
                                                       0, 0, 0);
        }
        __builtin_amdgcn_s_setprio(0);
      }

      __syncthreads();  // lands prefetch (vmcnt) + guards buf reuse
      cur ^= 1;
    }

    // ---- merge kh=1 partial into kh=0 via LDS scratch (= consumed buf) ----
    // O_b in bf16: Klds[cur^1] (64 rows x 128 B = exactly 8 KB).
    // m/l pairs: first 512 B of Vlds[cur^1] (fully free otherwise).
    {
      __hip_bfloat16* osb = &Klds[cur ^ 1][0];   // [q][d] bf16
      float* ml = (float*)&Vlds[cur ^ 1][0];     // [q][2]
      const int q = rh * 32 + r31;
      if (kh == 1) {
        if (a5 == 0) {
          ml[q * 2] = m_r;
          ml[q * 2 + 1] = l_r;
        }
        __hip_bfloat16* orow = osb + q * 64;
#pragma unroll
        for (int q2 = 0; q2 < 4; ++q2) {
          uint2 w;
          w.x = pack_bf2(o0[q2 * 4 + 0], o0[q2 * 4 + 1]);
          w.y = pack_bf2(o0[q2 * 4 + 2], o0[q2 * 4 + 3]);
          *(uint2*)(orow + 8 * q2 + 4 * a5) = w;
          w.x = pack_bf2(o1[q2 * 4 + 0], o1[q2 * 4 + 1]);
          w.y = pack_bf2(o1[q2 * 4 + 2], o1[q2 * 4 + 3]);
          *(uint2*)(orow + 32 + 8 * q2 + 4 * a5) = w;
        }
      }
      __syncthreads();
      if (kh == 0) {
        const float m_b = ml[q * 2];
        const float l_b = ml[q * 2 + 1];
        const float mn = fmaxf(m_r, m_b);
        const float aa = __builtin_amdgcn_exp2f(m_r - mn);
        const float ab = __builtin_amdgcn_exp2f(m_b - mn);
        const float lt = l_r * aa + l_b * ab;
        const float rl = __builtin_amdgcn_rcpf(lt);
        const float fa = aa * rl, fb = ab * rl;
        const __hip_bfloat16* orow = osb + q * 64;
        __hip_bfloat16* crow = ctx + ((size_t)b * S_ + qrow) * D_ + h * HD_;
#pragma unroll
        for (int q2 = 0; q2 < 4; ++q2) {
          uint2 v0 = *(const uint2*)(orow + 8 * q2 + 4 * a5);
          uint2 v1 = *(const uint2*)(orow + 32 + 8 * q2 + 4 * a5);
          uint2 w;
          w.x = pack_bf2(o0[q2 * 4 + 0] * fa + bf_lo(v0.x) * fb,
                         o0[q2 * 4 + 1] * fa + bf_hi(v0.x) * fb);
          w.y = pack_bf2(o0[q2 * 4 + 2] * fa + bf_lo(v0.y) * fb,
                         o0[q2 * 4 + 3] * fa + bf_hi(v0.y) * fb);
          *(uint2*)(crow + 8 * q2 + 4 * a5) = w;
          w.x = pack_bf2(o1[q2 * 4 + 0] * fa + bf_lo(v1.x) * fb,
                         o1[q2 * 4 + 1] * fa + bf_hi(v1.x) * fb);
          w.y = pack_bf2(o1[q2 * 4 + 2] * fa + bf_lo(v1.y) * fb,
                         o1[q2 * 4 + 3] * fa + bf_hi(v1.y) * fb);
          *(uint2*)(crow + 32 + 8 * q2 + 4 * a5) = w;
        }
      }
      __syncthreads();  // protect scratch from next sel's prefetch
    }
  }
#undef MKFRAG
}

// --------------------------------------------------------------- launch ----
extern "C" void kernel_launch(void* const* d_in, const int* in_sizes, int n_in,
                              void* d_out, int out_size, void* d_ws,
                              size_t ws_size, hipStream_t stream) {
  const float* x      = (const float*)d_in[0];
  const float* w_qkv  = (const float*)d_in[1];
  const float* b_qkv  = (const float*)d_in[2];
  const float* w_proj = (const float*)d_in[3];
  const float* b_proj = (const float*)d_in[4];
  float* out = (float*)d_out;

  char* ws = (char*)d_ws;
  __hip_bfloat16* xb     = (__hip_bfloat16*)(ws + 0);          // 16 MB
  __hip_bfloat16* wqkvT  = (__hip_bfloat16*)(ws + 16777216);   // 6 MB
  __hip_bfloat16* wprojT = (__hip_bfloat16*)(ws + 23068672);   // 2 MB
  __hip_bfloat16* qkvb   = (__hip_bfloat16*)(ws + 25165824);   // 50.3 MB
  __hip_bfloat16* ctx    = (__hip_bfloat16*)(ws + 75497472);   // 16 MB
  __hip_bfloat16* vt2    = (__hip_bfloat16*)(ws + 91750400);   // 16 MB

  // one fused prep launch: cast (8192 blocks) + wqkv T (3072) + wproj T (1024)
  prep_fused<<<8192 + 3072 + 1024, 256, 0, stream>>>(
      x, xb, w_qkv, wqkvT, w_proj, wprojT);

  gemm_bt_bias<__hip_bfloat16, true, 128>
      <<<dim3(N3_ / 128, M_ / 128), 256, 0, stream>>>(
          xb, wqkvT, b_qkv, qkvb, vt2, M_, N3_, D_);

  attn_causal<<<1024, 256, 0, stream>>>(qkvb, vt2, ctx);

  // G2 with BM=64: grid 8 x 128 = 1024 blocks = 4 blocks/CU
  gemm_bt_bias<float, false, 64>
      <<<dim3(D_ / 128, M_ / 64), 256, 0, stream>>>(
          ctx, wprojT, b_proj, out, (__hip_bfloat16*)nullptr, M_, D_, D_);
}